// Round 9
// baseline (380.201 us; speedup 1.0000x reference)
//
#include <hip/hip_runtime.h>

constexpr int B = 32, C = 64, N = 8192, R = 32, R3 = R * R * R;
constexpr int QUAR = R3 / 4;  // 8192 voxels -> 32 KB LDS slab
constexpr int T = 512;        // accum block size
constexpr int PPT = N / T;    // 16 points per thread (packed register cache)

// ---- workspace layout (needs ~6 MB) ---------------------------------------
constexpr size_t CNT_OFF = 0;                               // B*R3 u32 (4 MB)
constexpr size_t IDX_OFF = (size_t)B * R3 * 4;              // B*N u16 (512 KB)
constexpr size_t PF_OFF  = IDX_OFF + (size_t)B * N * 2;     // B*N f32 (1 MB)
constexpr size_t PRM_OFF = PF_OFF + (size_t)B * N * 4;      // B*4 f32

// ---------------------------------------------------------------------------
// K1: per-batch stats. Mean in f64; downstream replicates numpy f32 exactly
// (__f*_rn forbids FMA contraction; sum order matches np.linalg.norm).
// ---------------------------------------------------------------------------
__global__ __launch_bounds__(1024) void stats_kernel(
    const float* __restrict__ coords, float* __restrict__ params) {
  const int b = blockIdx.x;
  const int t = threadIdx.x;
  const float* cb = coords + (size_t)b * 3 * N;
  __shared__ double sm[1024];
  __shared__ float smf[1024];

  double sx = 0.0, sy = 0.0, sz = 0.0;
  for (int n = t; n < N; n += 1024) {
    sx += (double)cb[n];
    sy += (double)cb[N + n];
    sz += (double)cb[2 * N + n];
  }
  float mean[3];
  double vals[3] = {sx, sy, sz};
  for (int d = 0; d < 3; ++d) {
    sm[t] = vals[d];
    __syncthreads();
    for (int s = 512; s > 0; s >>= 1) {
      if (t < s) sm[t] += sm[t + s];
      __syncthreads();
    }
    mean[d] = (float)(sm[0] / (double)N);
    __syncthreads();
  }

  float mx = 0.0f;
  for (int n = t; n < N; n += 1024) {
    float dx = __fsub_rn(cb[n], mean[0]);
    float dy = __fsub_rn(cb[N + n], mean[1]);
    float dz = __fsub_rn(cb[2 * N + n], mean[2]);
    float n2 = __fadd_rn(__fadd_rn(__fmul_rn(dx, dx), __fmul_rn(dy, dy)),
                         __fmul_rn(dz, dz));
    mx = fmaxf(mx, n2);
  }
  smf[t] = mx;
  __syncthreads();
  for (int s = 512; s > 0; s >>= 1) {
    if (t < s) smf[t] = fmaxf(smf[t], smf[t + s]);
    __syncthreads();
  }
  if (t == 0) {
    float maxn = __fsqrt_rn(smf[0]);
    params[b * 4 + 0] = mean[0];
    params[b * 4 + 1] = mean[1];
    params[b * 4 + 2] = mean[2];
    params[b * 4 + 3] = __fmul_rn(maxn, 2.0f);  // denominator (EPS == 0)
  }
}

// ---------------------------------------------------------------------------
// K2: per-point voxel id (u16, within-batch) + count atomic + norm_coords.
// ---------------------------------------------------------------------------
__global__ __launch_bounds__(256) void voxelize_kernel(
    const float* __restrict__ coords, const float* __restrict__ params,
    float* __restrict__ ncout, unsigned short* __restrict__ idx,
    unsigned int* __restrict__ cnt) {
  const int i = blockIdx.x * 256 + threadIdx.x;  // [0, B*N)
  const int b = i >> 13;                         // N = 8192
  const int n = i & (N - 1);
  const float* cb = coords + (size_t)b * 3 * N;
  const float m0 = params[b * 4 + 0];
  const float m1 = params[b * 4 + 1];
  const float m2 = params[b * 4 + 2];
  const float dn = params[b * 4 + 3];

  float t0 = __fmul_rn(__fadd_rn(__fdiv_rn(__fsub_rn(cb[n], m0), dn), 0.5f), 32.0f);
  float t1 = __fmul_rn(__fadd_rn(__fdiv_rn(__fsub_rn(cb[N + n], m1), dn), 0.5f), 32.0f);
  float t2 = __fmul_rn(__fadd_rn(__fdiv_rn(__fsub_rn(cb[2 * N + n], m2), dn), 0.5f), 32.0f);
  t0 = fminf(fmaxf(t0, 0.0f), 31.0f);
  t1 = fminf(fmaxf(t1, 0.0f), 31.0f);
  t2 = fminf(fmaxf(t2, 0.0f), 31.0f);

  ncout[(size_t)b * 3 * N + n] = t0;
  ncout[(size_t)b * 3 * N + N + n] = t1;
  ncout[(size_t)b * 3 * N + 2 * N + n] = t2;

  const int vx = (int)rintf(t0);  // half-to-even == np.round
  const int vy = (int)rintf(t1);
  const int vz = (int)rintf(t2);
  const int flat = (vx * R + vy) * R + vz;  // [0, 32768)
  idx[i] = (unsigned short)flat;
  atomicAdd(&cnt[b * R3 + flat], 1u);
}

// ---------------------------------------------------------------------------
// K2.5: per-point reciprocal count. pf[i] = 1/max(cnt[voxel(i)],1).
// avg = sum(f * 1/c): moves the divide off accum's store path entirely.
// ---------------------------------------------------------------------------
__global__ __launch_bounds__(256) void invp_kernel(
    const unsigned short* __restrict__ idx,
    const unsigned int* __restrict__ cnt, float* __restrict__ pf) {
  const int i = blockIdx.x * 256 + threadIdx.x;  // [0, B*N)
  const int b = i >> 13;
  const unsigned int k = cnt[b * R3 + (int)idx[i]];
  pf[i] = __fdiv_rn(1.0f, (float)(k ? k : 1u));
}

// ---------------------------------------------------------------------------
// K3: one block per (b,c), 512 threads, 32 KB quarter-grid slab, 4 passes.
// Register cache: 8 uint = 16 packed u16 voxel ids, 8 float2 = 16 pre-scaled
// features. launch_bounds(512,8) caps VGPR at 64 -> 4 blocks/CU (128 KB LDS,
// 32 waves): store phases of some blocks overlap LDS phases of others.
// Zero is fused into the dump (read, write 0 back, store) -- one LDS phase
// and one barrier fewer per pass; same-wave same-address LDS ops are
// processed in order, so the read-then-zero is safe.
// ---------------------------------------------------------------------------
__global__ __launch_bounds__(512, 8) void accum_kernel(
    const float* __restrict__ feats, const unsigned short* __restrict__ idx,
    const float* __restrict__ pf, float* __restrict__ voxout) {
  __shared__ float lds[QUAR];
  const int blk = blockIdx.x;  // b*C + c
  const int c = blk & (C - 1);
  const int b = blk >> 6;
  const int t = threadIdx.x;

  // packed register cache (coalesced: consecutive lanes, consecutive pairs)
  const unsigned int* ib32 = (const unsigned int*)(idx + (size_t)b * N);
  const float2* pb2 = (const float2*)(pf + (size_t)b * N);
  const float2* fb2 = (const float2*)(feats + ((size_t)b * C + c) * N);
  unsigned int ivw[PPT / 2];
  float2 fv2[PPT / 2];
#pragma unroll
  for (int k = 0; k < PPT / 2; ++k) {
    const int j = t + k * T;  // pair index; covers points 2j, 2j+1
    ivw[k] = ib32[j];
    const float2 f = fb2[j];
    const float2 p = pb2[j];
    fv2[k] = {f.x * p.x, f.y * p.y};
  }

  float4* lp = (float4*)lds;
  const float4 z = {0.f, 0.f, 0.f, 0.f};

  // initial zero of the (poisoned) slab
#pragma unroll
  for (int k = t; k < QUAR / 4; k += T) lp[k] = z;
  __syncthreads();

  for (int h = 0; h < 4; ++h) {
    const int lo = h * QUAR;

    // scatter from registers (ds_add_f32; no global traffic)
#pragma unroll
    for (int k = 0; k < PPT / 2; ++k) {
      const int i0 = (int)(ivw[k] & 0xFFFFu) - lo;
      const int i1 = (int)(ivw[k] >> 16) - lo;
      if ((unsigned)i0 < (unsigned)QUAR) atomicAdd(&lds[i0], fv2[k].x);
      if ((unsigned)i1 < (unsigned)QUAR) atomicAdd(&lds[i1], fv2[k].y);
    }
    __syncthreads();

    // fused dump + re-zero: coalesced 32 KB store of the exclusive slice
    float4* ob4 = (float4*)(voxout + ((size_t)b * C + c) * R3 + lo);
#pragma unroll
    for (int v = t; v < QUAR / 4; v += T) {
      const float4 o = lp[v];
      lp[v] = z;        // same wave, same address: ordered after the read
      ob4[v] = o;
    }
    __syncthreads();
  }
}

extern "C" void kernel_launch(void* const* d_in, const int* in_sizes, int n_in,
                              void* d_out, int out_size, void* d_ws,
                              size_t ws_size, hipStream_t stream) {
  const float* feats  = (const float*)d_in[0];  // [B, C, N]
  const float* coords = (const float*)d_in[1];  // [B, 3, N]

  float* voxout = (float*)d_out;                // [B, C, R,R,R]
  float* ncout  = voxout + (size_t)B * C * R3;  // [B, 3, N]

  char* ws = (char*)d_ws;
  unsigned int* cnt   = (unsigned int*)(ws + CNT_OFF);
  unsigned short* idx = (unsigned short*)(ws + IDX_OFF);
  float* pf           = (float*)(ws + PF_OFF);
  float* params       = (float*)(ws + PRM_OFF);

  hipMemsetAsync(cnt, 0, (size_t)B * R3 * sizeof(unsigned int), stream);
  stats_kernel<<<B, 1024, 0, stream>>>(coords, params);
  voxelize_kernel<<<(B * N) / 256, 256, 0, stream>>>(coords, params, ncout,
                                                     idx, cnt);
  invp_kernel<<<(B * N) / 256, 256, 0, stream>>>(idx, cnt, pf);
  accum_kernel<<<B * C, T, 0, stream>>>(feats, idx, pf, voxout);
}